// Round 1
// baseline (622.556 us; speedup 1.0000x reference)
//
#include <hip/hip_runtime.h>
#include <cstdint>
#include <cstddef>

#define DEV static __device__ __forceinline__

typedef __attribute__((ext_vector_type(8))) short bf16x8_t;
typedef __attribute__((ext_vector_type(4))) float f32x4_t;

DEV unsigned short f2bf(float f) {
  union { float f; unsigned u; } v; v.f = f;
  unsigned r = v.u + 0x7fffu + ((v.u >> 16) & 1u);
  return (unsigned short)(r >> 16);
}
DEV float bf2f(unsigned short h) {
  union { unsigned u; float f; } v; v.u = ((unsigned)h) << 16;
  return v.f;
}

// async global->LDS, 16B per lane; LDS dest = wave-uniform base + lane*16
DEV void gl_lds16(const void* g, void* l) {
  __builtin_amdgcn_global_load_lds(
      (const __attribute__((address_space(1))) void*)g,
      (__attribute__((address_space(3))) void*)l,
      16, 0, 0);
}

// ---------------- cast fp32 -> bf16 (vectorized) ----------------
__global__ void cast_bf16_k(const float* __restrict__ src,
                            unsigned short* __restrict__ dst, int n4) {
  int i = blockIdx.x * blockDim.x + threadIdx.x;
  if (i < n4) {
    float4 f = ((const float4*)src)[i];
    ushort4 o;
    o.x = f2bf(f.x); o.y = f2bf(f.y); o.z = f2bf(f.z); o.w = f2bf(f.w);
    ((ushort4*)dst)[i] = o;
  }
}

// ---------------- transpose + cast: src [R,C] fp32 -> dst [C,R] bf16 --------
__global__ void tcast_k(const float* __restrict__ src,
                        unsigned short* __restrict__ dst, int R, int C) {
  __shared__ float tile[32][33];
  int tx = threadIdx.x & 31, ty = threadIdx.x >> 5;  // 256 thr: ty 0..7
  int c0 = blockIdx.x * 32, r0 = blockIdx.y * 32;
  for (int yy = ty; yy < 32; yy += 8)
    tile[yy][tx] = src[(size_t)(r0 + yy) * C + (c0 + tx)];
  __syncthreads();
  for (int yy = ty; yy < 32; yy += 8)
    dst[(size_t)(c0 + yy) * R + (r0 + tx)] = f2bf(tile[tx][yy]);
}

// ---------------- 128x128 bf16 MFMA GEMM, two epilogues ----------------
// A: [M,K] bf16 row-major (lda=K). W: [V,K] bf16 row-major (B = W^T).
// REDUCE: per-token online-LSE partials over this block's 128 vocab cols
//         + target-logit gather.  !REDUCE: store C as bf16 [M,V].
template <bool REDUCE>
__global__ __launch_bounds__(256)
void gemm128_k(const unsigned short* __restrict__ A,
               const unsigned short* __restrict__ W,
               const float* __restrict__ bias,
               int K, int V, int ntiles,
               float2* __restrict__ partials,   // [M][ntiles]
               float* __restrict__ gathered,    // [M]
               const int* __restrict__ target,
               int glo, int ghi, int gclamp,    // gclamp>=0: head mode (min(t,gclamp))
               unsigned short* __restrict__ Cout) {
  __shared__ __align__(16) unsigned short As[128 * 32];
  __shared__ __align__(16) unsigned short Bs[128 * 32];
  __shared__ float red[2][128][2];

  const int tid  = threadIdx.x;
  const int wid  = tid >> 6;
  const int lane = tid & 63;
  const int quad = lane >> 4;
  const int l16  = lane & 15;
  const int wr = wid >> 1, wc = wid & 1;
  const int tn = blockIdx.x, tm = blockIdx.y;
  const int m0 = tm * 128, n0 = tn * 128;

  f32x4_t acc[4][4];
  const f32x4_t zero4 = {0.f, 0.f, 0.f, 0.f};
#pragma unroll
  for (int i = 0; i < 4; ++i)
#pragma unroll
    for (int j = 0; j < 4; ++j) acc[i][j] = zero4;

  // staging: each wave fills 2KB of As and Bs (2 x 1KB gl_lds each)
  const int srow = wid * 32 + (lane >> 2);   // rows 0..111 (+16 for 2nd inst)
  const int skk  = (lane & 3) * 8;
  const unsigned short* Ap0 = A + (size_t)(m0 + srow) * K + skk;
  const unsigned short* Ap1 = A + (size_t)(m0 + srow + 16) * K + skk;
  int wrow0 = n0 + srow;      if (wrow0 > V - 1) wrow0 = V - 1;
  int wrow1 = n0 + srow + 16; if (wrow1 > V - 1) wrow1 = V - 1;
  const unsigned short* Wp0 = W + (size_t)wrow0 * K + skk;
  const unsigned short* Wp1 = W + (size_t)wrow1 * K + skk;
  unsigned short* Asw = As + wid * 1024;
  unsigned short* Bsw = Bs + wid * 1024;

  for (int k0 = 0; k0 < K; k0 += 32) {
    gl_lds16(Ap0, Asw);
    gl_lds16(Ap1, Asw + 512);
    gl_lds16(Wp0, Bsw);
    gl_lds16(Wp1, Bsw + 512);
    Ap0 += 32; Ap1 += 32; Wp0 += 32; Wp1 += 32;
    __syncthreads();
    bf16x8_t af[4], bfr[4];
#pragma unroll
    for (int i = 0; i < 4; ++i)
      af[i] = *(const bf16x8_t*)(As + (size_t)(wr * 64 + i * 16 + l16) * 32 + quad * 8);
#pragma unroll
    for (int j = 0; j < 4; ++j)
      bfr[j] = *(const bf16x8_t*)(Bs + (size_t)(wc * 64 + j * 16 + l16) * 32 + quad * 8);
#pragma unroll
    for (int i = 0; i < 4; ++i)
#pragma unroll
      for (int j = 0; j < 4; ++j)
        acc[i][j] = __builtin_amdgcn_mfma_f32_16x16x32_bf16(af[i], bfr[j], acc[i][j], 0, 0, 0);
    __syncthreads();
  }

  if (REDUCE) {
    int nj[4]; float bj[4];
#pragma unroll
    for (int j = 0; j < 4; ++j) {
      nj[j] = n0 + wc * 64 + j * 16 + l16;
      bj[j] = (nj[j] < V) ? bias[nj[j]] : 0.f;
    }
#pragma unroll
    for (int i = 0; i < 4; ++i) {
#pragma unroll
      for (int r = 0; r < 4; ++r) {
        const int row = wr * 64 + i * 16 + quad * 4 + r;
        const int token = m0 + row;
        float v[4];
        float mx = -1e30f;
#pragma unroll
        for (int j = 0; j < 4; ++j) {
          float x = (nj[j] < V) ? (acc[i][j][r] + bj[j]) : -1e30f;
          v[j] = x;
          mx = fmaxf(mx, x);
        }
#pragma unroll
        for (int off = 1; off < 16; off <<= 1)
          mx = fmaxf(mx, __shfl_xor(mx, off, 64));
        float s = 0.f;
#pragma unroll
        for (int j = 0; j < 4; ++j)
          if (v[j] > -1e29f) s += __expf(v[j] - mx);
#pragma unroll
        for (int off = 1; off < 16; off <<= 1)
          s += __shfl_xor(s, off, 64);
        if (l16 == 0) { red[wc][row][0] = mx; red[wc][row][1] = s; }
        const int t = target[token];
        const int gi = (gclamp >= 0) ? ((t < gclamp) ? t : gclamp)
                                     : ((t >= glo && t < ghi) ? (t - glo) : -1);
        if (gi >= 0) {
#pragma unroll
          for (int j = 0; j < 4; ++j)
            if (nj[j] == gi) gathered[token] = v[j];
        }
      }
    }
    __syncthreads();
    if (tid < 128) {
      float m1 = red[0][tid][0], s1 = red[0][tid][1];
      float m2 = red[1][tid][0], s2 = red[1][tid][1];
      float M = fmaxf(m1, m2);
      float S = s1 * __expf(m1 - M) + s2 * __expf(m2 - M);
      partials[(size_t)(m0 + tid) * ntiles + tn] = make_float2(M, S);
    }
  } else {
#pragma unroll
    for (int i = 0; i < 4; ++i)
#pragma unroll
      for (int j = 0; j < 4; ++j) {
        const int n = n0 + wc * 64 + j * 16 + l16;
        if (n < V) {
#pragma unroll
          for (int r = 0; r < 4; ++r) {
            const int m = m0 + wr * 64 + i * 16 + quad * 4 + r;
            Cout[(size_t)m * V + n] = f2bf(acc[i][j][r]);
          }
        }
      }
  }
}

// ---------------- combine: fold partials -> nll per token ----------------
__global__ __launch_bounds__(256)
void combine_k(const float2* __restrict__ part0, int nt0,
               const float2* __restrict__ part1, int nt1,
               const float2* __restrict__ part2, int nt2,
               const float* __restrict__ g0, const float* __restrict__ g1,
               const float* __restrict__ g2,
               const unsigned short* __restrict__ P0b,
               const float* __restrict__ cw, const float* __restrict__ cb,
               const int* __restrict__ target,
               float* __restrict__ out) {
  __shared__ float sa[256], sb[256];
  __shared__ float cshared[2];
  const int token = blockIdx.x;
  const int tid = threadIdx.x;
  const int t = target[token];

  // cluster logits c0 = p0 . cw[0], c1 = p0 . cw[1]
  float a0 = 0.f, a1 = 0.f;
  for (int k = tid; k < 1024; k += 256) {
    float p = bf2f(P0b[(size_t)token * 1024 + k]);
    a0 += p * cw[k];
    a1 += p * cw[1024 + k];
  }
  sa[tid] = a0; sb[tid] = a1;
  __syncthreads();
  for (int s = 128; s > 0; s >>= 1) {
    if (tid < s) { sa[tid] += sa[tid + s]; sb[tid] += sb[tid + s]; }
    __syncthreads();
  }
  if (tid == 0) { cshared[0] = sa[0] + cb[0]; cshared[1] = sb[0] + cb[1]; }
  __syncthreads();
  const float c0 = cshared[0], c1 = cshared[1];

  // head LSE over nt0 partials + the two cluster logits
  float M = -1e30f, S = 0.f;
  for (int i2 = tid; i2 < nt0; i2 += 256) {
    float2 e = part0[(size_t)token * nt0 + i2];
    float Mn = fmaxf(M, e.x);
    S = S * __expf(M - Mn) + e.y * __expf(e.x - Mn);
    M = Mn;
  }
  if (tid == 0) { float Mn = fmaxf(M, c0); S = S * __expf(M - Mn) + __expf(c0 - Mn); M = Mn; }
  if (tid == 1) { float Mn = fmaxf(M, c1); S = S * __expf(M - Mn) + __expf(c1 - Mn); M = Mn; }
  __syncthreads();
  sa[tid] = M; sb[tid] = S;
  __syncthreads();
  for (int s = 128; s > 0; s >>= 1) {
    if (tid < s) {
      float m1 = sa[tid], s1v = sb[tid], m2 = sa[tid + s], s2v = sb[tid + s];
      float Mn = fmaxf(m1, m2);
      sa[tid] = Mn;
      sb[tid] = s1v * __expf(m1 - Mn) + s2v * __expf(m2 - Mn);
    }
    __syncthreads();
  }
  const float lse_head = sa[0] + __logf(sb[0]);

  float result;
  if (t < 20000) {
    result = lse_head - g0[token];
  } else {
    const float2* pt; int nt; const float* gv; float ch;
    if (t < 50000) { pt = part1; nt = nt1; gv = g1; ch = c1; }  // head_lp[:,-1] -> idx 20001
    else           { pt = part2; nt = nt2; gv = g2; ch = c0; }  // head_lp[:,-2] -> idx 20000
    float M2 = -1e30f, S2 = 0.f;
    for (int i2 = tid; i2 < nt; i2 += 256) {
      float2 e = pt[(size_t)token * nt + i2];
      float Mn = fmaxf(M2, e.x);
      S2 = S2 * __expf(M2 - Mn) + e.y * __expf(e.x - Mn);
      M2 = Mn;
    }
    __syncthreads();
    sa[tid] = M2; sb[tid] = S2;
    __syncthreads();
    for (int s = 128; s > 0; s >>= 1) {
      if (tid < s) {
        float m1 = sa[tid], s1v = sb[tid], m2 = sa[tid + s], s2v = sb[tid + s];
        float Mn = fmaxf(m1, m2);
        sa[tid] = Mn;
        sb[tid] = s1v * __expf(m1 - Mn) + s2v * __expf(m2 - Mn);
      }
      __syncthreads();
    }
    float lse_t = sa[0] + __logf(sb[0]);
    result = -((ch - lse_head) + (gv[token] - lse_t));
  }
  if (tid == 0) out[token] = result;
}

extern "C" void kernel_launch(void* const* d_in, const int* in_sizes, int n_in,
                              void* d_out, int out_size, void* d_ws, size_t ws_size,
                              hipStream_t stream) {
  (void)in_sizes; (void)n_in; (void)out_size; (void)ws_size;
  const float* hidden = (const float*)d_in[0];
  const int*   target = (const int*)d_in[1];
  const float* w0     = (const float*)d_in[2];
  const float* b0     = (const float*)d_in[3];
  const float* cw     = (const float*)d_in[4];
  const float* cb     = (const float*)d_in[5];
  const float* proj0  = (const float*)d_in[6];
  const float* w1     = (const float*)d_in[7];
  const float* b1     = (const float*)d_in[8];
  const float* proj1  = (const float*)d_in[9];
  const float* w2     = (const float*)d_in[10];
  const float* b2     = (const float*)d_in[11];
  const float* proj2  = (const float*)d_in[12];
  float* out = (float*)d_out;

  // ws carve-up (~88 MB total)
  char* p = (char*)d_ws;
  auto alloc = [&](size_t bytes) {
    char* r = p; p += (bytes + 255) & ~(size_t)255; return r;
  };
  unsigned short* Hb  = (unsigned short*)alloc(2048ull * 1024 * 2);
  unsigned short* p0T = (unsigned short*)alloc(1024ull * 1024 * 2);
  unsigned short* p1T = (unsigned short*)alloc(256ull * 1024 * 2);
  unsigned short* p2T = (unsigned short*)alloc(64ull * 1024 * 2);
  unsigned short* w0b = (unsigned short*)alloc(20000ull * 1024 * 2);
  unsigned short* w1b = (unsigned short*)alloc(30000ull * 256 * 2);
  unsigned short* w2b = (unsigned short*)alloc(50000ull * 64 * 2);
  unsigned short* P0b = (unsigned short*)alloc(2048ull * 1024 * 2);
  unsigned short* P1b = (unsigned short*)alloc(2048ull * 256 * 2);
  unsigned short* P2b = (unsigned short*)alloc(2048ull * 64 * 2);
  float2* part0 = (float2*)alloc(2048ull * 157 * 8);
  float2* part1 = (float2*)alloc(2048ull * 235 * 8);
  float2* part2 = (float2*)alloc(2048ull * 391 * 8);
  float* g0 = (float*)alloc(2048 * 4);
  float* g1 = (float*)alloc(2048 * 4);
  float* g2 = (float*)alloc(2048 * 4);

  auto cast = [&](const float* s, unsigned short* d, int n) {
    int n4 = n / 4;
    cast_bf16_k<<<(n4 + 255) / 256, 256, 0, stream>>>(s, d, n4);
  };
  cast(hidden, Hb, 2048 * 1024);
  cast(w0, w0b, 20000 * 1024);
  cast(w1, w1b, 30000 * 256);
  cast(w2, w2b, 50000 * 64);
  tcast_k<<<dim3(1024 / 32, 1024 / 32), 256, 0, stream>>>(proj0, p0T, 1024, 1024);
  tcast_k<<<dim3(256 / 32, 1024 / 32), 256, 0, stream>>>(proj1, p1T, 1024, 256);
  tcast_k<<<dim3(64 / 32, 1024 / 32), 256, 0, stream>>>(proj2, p2T, 1024, 64);

  // projections: P = Hb @ projT^T  (projT row-major [Nout, 1024])
  gemm128_k<false><<<dim3(8, 16), 256, 0, stream>>>(Hb, p0T, nullptr, 1024, 1024, 0,
      nullptr, nullptr, nullptr, 0, 0, -1, P0b);
  gemm128_k<false><<<dim3(2, 16), 256, 0, stream>>>(Hb, p1T, nullptr, 1024, 256, 0,
      nullptr, nullptr, nullptr, 0, 0, -1, P1b);
  gemm128_k<false><<<dim3(1, 16), 256, 0, stream>>>(Hb, p2T, nullptr, 1024, 64, 0,
      nullptr, nullptr, nullptr, 0, 0, -1, P2b);

  // vocab GEMMs with fused online-LSE partials + target gather
  gemm128_k<true><<<dim3(157, 16), 256, 0, stream>>>(P0b, w0b, b0, 1024, 20000, 157,
      part0, g0, target, 0, 0, 19999, nullptr);
  gemm128_k<true><<<dim3(235, 16), 256, 0, stream>>>(P1b, w1b, b1, 256, 30000, 235,
      part1, g1, target, 20000, 50000, -1, nullptr);
  gemm128_k<true><<<dim3(391, 16), 256, 0, stream>>>(P2b, w2b, b2, 64, 50000, 391,
      part2, g2, target, 50000, 100000, -1, nullptr);

  combine_k<<<2048, 256, 0, stream>>>(part0, 157, part1, 235, part2, 391,
      g0, g1, g2, P0b, cw, cb, target, out);
}